// Round 13
// baseline (755.864 us; speedup 1.0000x reference)
//
#include <hip/hip_runtime.h>
#include <hip/hip_bf16.h>
#include <math.h>

#define NCHUNK 22
#define SEQLEN 600
#define BN_EPS 1e-5f

// ws offsets (4-byte units)
#define OFF_W1F    0         // 1024   u32 : conv1 B dup-frags [ph2][pat2][lane][r]
#define OFF_W2F    1024      // 13312  u32 : conv2 32x32 B-frags [s26][hl2][lane][r4]
#define OFF_W3F    14336     // 51200  u32 : conv3 B-frags [s25][nt4][hl2][lane][r4]
#define OFF_MHF    65536     // 32768  u32 : Mh=WqT*Wk B-frags [h8][ks2][nt4][hl2][lane][r4]
#define OFF_WC     98304     // 32768  f32 : WC (final, by repack2)
#define OFF_UH     131072    // 512    f32 : u_h[h][d] = sum_e Wq[h,e,d]*bk[h,e]
#define OFF_WH     131584    // 512    f32 : w_h[h][d] = sum_e Wk[h,e,d]*bq[h,e]
#define OFF_CH     132096    // 8      f32 : c_h = bq.bk
#define OFF_CBIAS  132104    // 64     f32 : all-bias fold (cbias kernel)
#define OFF_WCOMB  132168    // 32768  f32 : Wcomb intermediate (repack)
#define OFF_FEAT   164936    // 2*B*22*64 u32 (PACKED hi|lo)
#define REPACK_N   132104

typedef short bf16x8 __attribute__((ext_vector_type(8)));
typedef float f32x4 __attribute__((ext_vector_type(4)));
typedef float f32x16 __attribute__((ext_vector_type(16)));

#if __has_builtin(__builtin_amdgcn_perm)
#define PERM_HI(r0, r1) __builtin_amdgcn_perm((r1), (r0), 0x05040100u)
#define PERM_LO(r0, r1) __builtin_amdgcn_perm((r1), (r0), 0x07060302u)
#else
#define PERM_HI(r0, r1) (((r0) & 0xFFFFu) | ((r1) << 16))
#define PERM_LO(r0, r1) (((r0) >> 16) | ((r1) & 0xFFFF0000u))
#endif

__device__ __forceinline__ float swishf(float z) {
    return z / (1.f + __expf(-z));
}
// HW RNE conversion (compiler emits v_cvt; pairs fuse to v_cvt_pk_bf16_f32)
__device__ __forceinline__ unsigned short bf16_rne(float f) {
    __hip_bfloat16 h = __float2bfloat16(f);
    unsigned short u; __builtin_memcpy(&u, &h, 2); return u;
}
__device__ __forceinline__ float bf16_tof(unsigned short h) {
    return __uint_as_float(((unsigned int)h) << 16);
}
// pack two floats -> u32 (low16 = bf16(f0), high16 = bf16(f1))
__device__ __forceinline__ unsigned int pk2(float f0, float f1) {
    __hip_bfloat162 b2;
    b2.x = __float2bfloat16(f0);
    b2.y = __float2bfloat16(f1);
    unsigned int r; __builtin_memcpy(&r, &b2, 4); return r;
}
// packed u32: low16 = hi-bf16, high16 = lo-bf16 (residual)
__device__ __forceinline__ unsigned int pack_hl(float f) {
    unsigned short h = bf16_rne(f);
    unsigned short l = bf16_rne(f - bf16_tof(h));
    return (unsigned int)h | ((unsigned int)l << 16);
}
__device__ __forceinline__ float unpk_f32(unsigned int w) {
    return __uint_as_float(w << 16) + __uint_as_float(w & 0xFFFF0000u);
}
__device__ __forceinline__ unsigned int dup_word(float f, int pat) {
    unsigned short h = bf16_rne(f);
    unsigned short v = pat ? bf16_rne(f - bf16_tof(h)) : h;
    return (unsigned int)v | ((unsigned int)v << 16);
}
__device__ __forceinline__ unsigned int frag_word(float f0, float f1, int hl) {
    unsigned short h0 = bf16_rne(f0), h1 = bf16_rne(f1);
    if (hl == 0) return (unsigned int)h0 | ((unsigned int)h1 << 16);
    unsigned short l0 = bf16_rne(f0 - bf16_tof(h0));
    unsigned short l1 = bf16_rne(f1 - bf16_tof(h1));
    return (unsigned int)l0 | ((unsigned int)l1 << 16);
}
__device__ __forceinline__ void frag_from_packed(const unsigned int* p, bf16x8& h8, bf16x8& l8) {
    unsigned int r0 = p[0], r1 = p[1], r2 = p[2], r3 = p[3];
    unsigned int r4 = p[4], r5 = p[5], r6 = p[6], r7 = p[7];
    union U { unsigned int w[4]; bf16x8 v; } H, L;
    H.w[0] = PERM_HI(r0, r1); H.w[1] = PERM_HI(r2, r3);
    H.w[2] = PERM_HI(r4, r5); H.w[3] = PERM_HI(r6, r7);
    L.w[0] = PERM_LO(r0, r1); L.w[1] = PERM_LO(r2, r3);
    L.w[2] = PERM_LO(r4, r5); L.w[3] = PERM_LO(r6, r7);
    h8 = H.v; l8 = L.v;
}

__global__ __launch_bounds__(256) void repack_kernel(
    const float* __restrict__ w1, const float* __restrict__ w2, const float* __restrict__ w3,
    const float* __restrict__ Wq, const float* __restrict__ Wk, const float* __restrict__ Wv,
    const float* __restrict__ Wfc, const float* __restrict__ Wout,
    const float* __restrict__ bq, const float* __restrict__ bk,
    float* __restrict__ ws)
{
    int tid = blockIdx.x * 256 + threadIdx.x;
    unsigned int* wsu = (unsigned int*)ws;
    if (tid < 1024) {                        // conv1 dup-B
        int r = tid & 3, lane = (tid >> 2) & 63, pat = (tid >> 8) & 1, ph = (tid >> 9) & 1;
        int li = lane & 15, lg = lane >> 4;
        int k = ph * 16 + lg * 4 + r;
        float f = (k < 26) ? w1[li * 26 + k] : 0.f;
        wsu[OFF_W1F + tid] = dup_word(f, pat);
    }
    int t2 = tid - 1024;
    if (t2 >= 0 && t2 < 13312) {             // conv2 32x32x16 B-frags
        int r = t2 & 3, lane = (t2 >> 2) & 63, hl = (t2 >> 8) & 1, s = t2 >> 9;
        int co = lane & 31;
        int ci0 = (lane >> 5) * 8;
        float f0 = w2[co * 416 + (ci0 + 2 * r) * 26 + s];
        float f1 = w2[co * 416 + (ci0 + 2 * r + 1) * 26 + s];
        wsu[OFF_W2F + t2] = frag_word(f0, f1, hl);
    }
    int t3 = tid - 14336;
    if (t3 >= 0 && t3 < 51200) {             // conv3 B-frags
        int r = t3 & 3, l = (t3 >> 2) & 63, hl = (t3 >> 8) & 1;
        int nt = (t3 >> 9) & 3, s = t3 >> 11;
        int co = nt * 16 + (l & 15);
        int k0 = s * 32 + (l >> 4) * 8 + 2 * r;
        float f0 = w3[co * 800 + (k0 & 31) * 25 + (k0 >> 5)];
        float f1 = w3[co * 800 + ((k0 + 1) & 31) * 25 + ((k0 + 1) >> 5)];
        wsu[OFF_W3F + t3] = frag_word(f0, f1, hl);
    }
    int t4 = tid - 65536;
    if (t4 >= 0 && t4 < 32768) {             // Mh B-frags
        int r = t4 & 3, l = (t4 >> 2) & 63, hl = (t4 >> 8) & 1;
        int nt = (t4 >> 9) & 3, ks = (t4 >> 11) & 1, h = t4 >> 12;
        int n = nt * 16 + (l & 15);
        int d0 = ks * 32 + (l >> 4) * 8 + 2 * r;
        const float* wqh = Wq + h * 4096;
        const float* wkh = Wk + h * 4096;
        float f0 = 0.f, f1 = 0.f;
        #pragma unroll 8
        for (int e = 0; e < 64; ++e) {
            float wk_en = wkh[e * 64 + n];
            f0 = fmaf(wqh[e * 64 + d0],     wk_en, f0);
            f1 = fmaf(wqh[e * 64 + d0 + 1], wk_en, f1);
        }
        wsu[OFF_MHF + t4] = frag_word(f0, f1, hl);
    }
    int t7 = tid - 98304;
    if (t7 >= 0 && t7 < 32768) {             // Wcomb[j][k] intermediate
        int k = t7 & 63, j = t7 >> 6;
        float acc = 0.f;
        #pragma unroll 8
        for (int d = 0; d < 64; ++d)
            acc = fmaf(Wfc[d * 512 + j], Wout[k * 64 + d], acc);
        ws[OFF_WCOMB + t7] = acc;
    }
    int t8 = tid - 131072;
    if (t8 >= 0 && t8 < 512) {               // u_h
        int h = t8 >> 6, d = t8 & 63;
        float acc = 0.f;
        #pragma unroll 8
        for (int e = 0; e < 64; ++e) acc = fmaf(Wq[h * 4096 + e * 64 + d], bk[h * 64 + e], acc);
        ws[OFF_UH + t8] = acc;
    }
    int t9 = tid - 131584;
    if (t9 >= 0 && t9 < 512) {               // w_h
        int h = t9 >> 6, d = t9 & 63;
        float acc = 0.f;
        #pragma unroll 8
        for (int e = 0; e < 64; ++e) acc = fmaf(Wk[h * 4096 + e * 64 + d], bq[h * 64 + e], acc);
        ws[OFF_WH + t9] = acc;
    }
    int t10 = tid - 132096;
    if (t10 >= 0 && t10 < 8) {               // c_h
        float acc = 0.f;
        #pragma unroll 8
        for (int e = 0; e < 64; ++e) acc = fmaf(bq[t10 * 64 + e], bk[t10 * 64 + e], acc);
        ws[OFF_CH + t10] = acc;
    }
}

// WC[h*64+d][k] = sum_e Wv[h,e,d] * Wcomb[(h*64+e)][k]
__global__ __launch_bounds__(256) void repack2_kernel(
    const float* __restrict__ Wv, float* __restrict__ ws)
{
    int tid = blockIdx.x * 256 + threadIdx.x;   // 32768
    int k = tid & 63, j = tid >> 6;
    int h = j >> 6, d = j & 63;
    const float* wcomb = ws + OFF_WCOMB + (size_t)(h * 64) * 64 + k;
    const float* wv = Wv + h * 4096 + d;
    float acc = 0.f;
    #pragma unroll 8
    for (int e = 0; e < 64; ++e)
        acc = fmaf(wv[e * 64], wcomb[e * 64], acc);
    ws[OFF_WC + tid] = acc;
}

// cbias'[k] = bout[k] + sum_dp (bfc[dp] + sum_j bv[j]*Wfc[dp][j]) * Wout[k][dp]
__global__ __launch_bounds__(64) void cbias_kernel(
    const float* __restrict__ Wfc, const float* __restrict__ Wout,
    const float* __restrict__ bfc, const float* __restrict__ bout,
    const float* __restrict__ bv, float* __restrict__ ws)
{
    __shared__ float sd_s[64];
    int t = threadIdx.x;
    float acc = 0.f;
    for (int j = 0; j < 512; ++j) acc = fmaf(bv[j], Wfc[t * 512 + j], acc);
    sd_s[t] = acc;
    __syncthreads();
    float cb = bout[t];
    #pragma unroll 8
    for (int dp = 0; dp < 64; ++dp) cb = fmaf(bfc[dp] + sd_s[dp], Wout[t * 64 + dp], cb);
    ws[OFF_CBIAS + t] = cb;
}

// Encoder: TWO tiles per block (R11/R12-proven, unchanged).
__global__ __launch_bounds__(256, 4) void encoder_kernel(
    const float* __restrict__ audio1, const float* __restrict__ audio2,
    const float* __restrict__ b1, const float* __restrict__ g1, const float* __restrict__ be1,
    const float* __restrict__ m1, const float* __restrict__ v1,
    const float* __restrict__ b2, const float* __restrict__ g2, const float* __restrict__ be2,
    const float* __restrict__ m2, const float* __restrict__ v2,
    const float* __restrict__ b3, const float* __restrict__ g3, const float* __restrict__ be3,
    const float* __restrict__ m3, const float* __restrict__ v3,
    float* __restrict__ ws, int B)
{
    __shared__ __align__(16) unsigned int smem[8816];
    unsigned int* a_p0 = smem;                               // [0,192)
    unsigned int* a_p1 = smem + 192;                         // [192,384)
    unsigned int* w2f  = smem + 384;                         // [384,2432) 2x1024 dbuf
    unsigned short* y1h0 = (unsigned short*)(smem + 2432);   // 154x20 u16
    unsigned short* y1l0 = (unsigned short*)(smem + 3972);
    unsigned short* y1h1 = (unsigned short*)(smem + 5512);
    unsigned short* y1l1 = (unsigned short*)(smem + 7052);   // ends 8592
    unsigned short* y2h0 = (unsigned short*)(smem + 384);    // ALIAS 5x808 u16
    unsigned short* y2l0 = (unsigned short*)(smem + 2404);
    unsigned short* y2h1 = (unsigned short*)(smem + 4424);
    unsigned short* y2l1 = (unsigned short*)(smem + 6444);   // ends 8464
    float* A_s  = (float*)(smem + 8592);                     // 112
    float* Bc_s = (float*)(smem + 8704);                     // 112

    int t = threadIdx.x;
    int blk = blockIdx.x;
    int g0 = blk * 2, g1v = g0 + 1;
    int seq0 = g0 / 5, tile0 = g0 - seq0 * 5;
    int seq1 = g1v / 5, tile1 = g1v - seq1 * 5;
    int tc0 = (tile0 == 4) ? 2 : 5, tc1 = (tile1 == 4) ? 2 : 5;
    int nq0 = 25 * tc0, nq1 = 25 * tc1;
    int ny10 = nq0 + 25, ny11 = nq1 + 25;
    int na0 = nq0 + 50, na1 = nq1 + 50;
    const unsigned int* wsu = (const unsigned int*)ws;
    int lane = t & 63, wid = t >> 6;
    int li = lane & 15, lg = lane >> 4;

    const float* aud0 = (seq0 < B ? audio1 + (size_t)seq0 * SEQLEN
                                  : audio2 + (size_t)(seq0 - B) * SEQLEN) + tile0 * 125;
    const float* aud1 = (seq1 < B ? audio1 + (size_t)seq1 * SEQLEN
                                  : audio2 + (size_t)(seq1 - B) * SEQLEN) + tile1 * 125;
    uint4 w1b[2][2];
    #pragma unroll
    for (int ph = 0; ph < 2; ++ph)
        #pragma unroll
        for (int pat = 0; pat < 2; ++pat)
            w1b[ph][pat] = *(const uint4*)(wsu + OFF_W1F + ((ph * 2 + pat) * 64 + lane) * 4);

    if (t < 192) {
        a_p0[t] = (t < na0) ? pack_hl(aud0[t]) : 0u;
        a_p1[t] = (t < na1) ? pack_hl(aud1[t]) : 0u;
    }
    *(uint4*)(w2f + t * 4) = *(const uint4*)(wsu + OFF_W2F + t * 4);   // stage 0
    if (t < 16)       { float A = g1[t] * rsqrtf(v1[t] + BN_EPS); A_s[t] = A; Bc_s[t] = (b1[t] - m1[t]) * A + be1[t]; }
    else if (t < 48)  { int i = t - 16; float A = g2[i] * rsqrtf(v2[i] + BN_EPS); A_s[t] = A; Bc_s[t] = (b2[i] - m2[i]) * A + be2[i]; }
    else if (t < 112) { int i = t - 48; float A = g3[i] * rsqrtf(v3[i] + BN_EPS); A_s[t] = A; Bc_s[t] = (b3[i] - m3[i]) * A + be3[i]; }
    for (int i = ny10 * 10 + t; i < 1540; i += 256) {
        (smem + 2432)[i] = 0u;
        (smem + 3972)[i] = 0u;
    }
    for (int i = ny11 * 10 + t; i < 1540; i += 256) {
        (smem + 5512)[i] = 0u;
        (smem + 7052)[i] = 0u;
    }
    __syncthreads();

    // ---- conv1 MFMA (dup-B) x2 tiles ----
    {
        float Ai = A_s[li], Bi = Bc_s[li];
        #pragma unroll
        for (int tl = 0; tl < 2; ++tl) {
            const unsigned int* ap_base = tl ? a_p1 : a_p0;
            unsigned short* yh = tl ? y1h1 : y1h0;
            unsigned short* yl = tl ? y1l1 : y1l0;
            int ny1 = tl ? ny11 : ny10;
            int nMt1 = (ny1 + 15) >> 4;
            for (int mt = wid; mt < nMt1; mt += 4) {
                f32x4 acc = {0.f, 0.f, 0.f, 0.f};
                #pragma unroll
                for (int ph = 0; ph < 2; ++ph) {
                    const unsigned int* ap = ap_base + mt * 16 + li + ph * 16 + lg * 4;
                    union { unsigned int w[4]; bf16x8 v; } A;
                    A.w[0] = ap[0]; A.w[1] = ap[1]; A.w[2] = ap[2]; A.w[3] = ap[3];
                    bf16x8 b0 = *(const bf16x8*)&w1b[ph][0];
                    bf16x8 b1 = *(const bf16x8*)&w1b[ph][1];
                    acc = __builtin_amdgcn_mfma_f32_16x16x32_bf16(A.v, b0, acc, 0, 0, 0);
                    acc = __builtin_amdgcn_mfma_f32_16x16x32_bf16(A.v, b1, acc, 0, 0, 0);
                }
                int p0 = mt * 16 + lg * 4;
                #pragma unroll
                for (int rg = 0; rg < 4; rg += 2) {
                    float f0 = swishf(fmaf(acc[rg],     Ai, Bi));
                    float f1 = swishf(fmaf(acc[rg + 1], Ai, Bi));
                    unsigned int hp = pk2(f0, f1);
                    unsigned int lp = pk2(f0 - bf16_tof((unsigned short)hp),
                                          f1 - bf16_tof((unsigned short)(hp >> 16)));
                    int p = p0 + rg;
                    if (p < ny1) {
                        yh[p * 20 + li] = (unsigned short)hp;
                        yl[p * 20 + li] = (unsigned short)lp;
                    }
                    if (p + 1 < ny1) {
                        yh[(p + 1) * 20 + li] = (unsigned short)(hp >> 16);
                        yl[(p + 1) * 20 + li] = (unsigned short)(lp >> 16);
                    }
                }
            }
        }
    }
    __syncthreads();

    // ---- conv2 MFMA 32x32x16: both tiles per stage (2 acc chains) ----
    int row0 = wid * 32 + (lane & 31);
    int ci0 = (lane >> 5) * 8;
    f32x16 accA, accB;
    #pragma unroll
    for (int r = 0; r < 16; ++r) { accA[r] = 0.f; accB[r] = 0.f; }

    for (int stg = 0; stg < 13; ++stg) {
        uint4 vnext;
        if (stg < 12)
            vnext = *(const uint4*)(wsu + OFF_W2F + (stg + 1) * 1024 + t * 4);
        const unsigned int* cur = w2f + (stg & 1) * 1024;
        #pragma unroll
        for (int half = 0; half < 2; ++half) {
            int s = stg * 2 + half;
            bf16x8 bh = *(const bf16x8*)(cur + half * 512 + lane * 4);
            bf16x8 bl = *(const bf16x8*)(cur + half * 512 + 256 + lane * 4);
            {   // tile 0
                const unsigned short* hp = y1h0 + (row0 + s) * 20 + ci0;
                const unsigned short* lp = y1l0 + (row0 + s) * 20 + ci0;
                union { uint2 u[2]; bf16x8 v; } Ah, Al;
                Ah.u[0] = *(const uint2*)hp; Ah.u[1] = *(const uint2*)(hp + 4);
                Al.u[0] = *(const uint2*)lp; Al.u[1] = *(const uint2*)(lp + 4);
                accA = __builtin_amdgcn_mfma_f32_32x32x16_bf16(Ah.v, bh, accA, 0, 0, 0);
                accA = __builtin_amdgcn_mfma_f32_32x32x16_bf16(Al.v, bh, accA, 0, 0, 0);
                accA = __builtin_amdgcn_mfma_f32_32x32x16_bf16(Ah.v, bl, accA, 0, 0, 0);
            }
            {   // tile 1
                const unsigned short* hp = y1h1 + (row0 + s) * 20 + ci0;
                const unsigned short* lp = y1l1 + (row0 + s) * 20 + ci0;
                union { uint2 u[2]; bf16x8 v; } Ah, Al;
                Ah.u[0] = *(const uint2*)hp; Ah.u[1] = *(const uint2*)(hp + 4);
                Al.u[0] = *(const uint2*)lp; Al.u[1] = *(const uint2*)(lp + 4);
                accB = __builtin_amdgcn_mfma_f32_32x32x16_bf16(Ah.v, bh, accB, 0, 0, 0);
                accB = __builtin_amdgcn_mfma_f32_32x32x16_bf16(Al.v, bh, accB, 0, 0, 0);
                accB = __builtin_amdgcn_mfma_f32_32x32x16_bf16(Ah.v, bl, accB, 0, 0, 0);
            }
        }
        if (stg < 12)
            *(uint4*)(w2f + ((stg + 1) & 1) * 1024 + t * 4) = vnext;
        __syncthreads();
    }
    // epilogue: y2 for both tiles, paired cvt_pk (aliases w2f+y1)
    {
        int co = lane & 31;
        float Ac = A_s[16 + co], Bc = Bc_s[16 + co];
        int rbase = 4 * (lane >> 5) + wid * 32;
        #pragma unroll
        for (int rg = 0; rg < 16; rg += 2) {
            int q0 = rbase + (rg & 3) + 8 * (rg >> 2);
            {   // tile 0
                float f0 = swishf(fmaf(accA[rg],     Ac, Bc));
                float f1 = swishf(fmaf(accA[rg + 1], Ac, Bc));
                unsigned int hp = pk2(f0, f1);
                unsigned int lp = pk2(f0 - bf16_tof((unsigned short)hp),
                                      f1 - bf16_tof((unsigned short)(hp >> 16)));
                if (q0 < nq0) {
                    int cc = q0 / 25, qp = q0 - cc * 25;
                    y2h0[cc * 808 + qp * 32 + co] = (unsigned short)hp;
                    y2l0[cc * 808 + qp * 32 + co] = (unsigned short)lp;
                }
                if (q0 + 1 < nq0) {
                    int cc = (q0 + 1) / 25, qp = (q0 + 1) - cc * 25;
                    y2h0[cc * 808 + qp * 32 + co] = (unsigned short)(hp >> 16);
                    y2l0[cc * 808 + qp * 32 + co] = (unsigned short)(lp >> 16);
                }
            }
            {   // tile 1
                float f0 = swishf(fmaf(accB[rg],     Ac, Bc));
                float f1 = swishf(fmaf(accB[rg + 1], Ac, Bc));
                unsigned int hp = pk2(f0, f1);
                unsigned int lp = pk2(f0 - bf16_tof((unsigned short)hp),
                                      f1 - bf16_tof((unsigned short)(hp >> 16)));
                if (q0 < nq1) {
                    int cc = q0 / 25, qp = q0 - cc * 25;
                    y2h1[cc * 808 + qp * 32 + co] = (unsigned short)hp;
                    y2l1[cc * 808 + qp * 32 + co] = (unsigned short)lp;
                }
                if (q0 + 1 < nq1) {
                    int cc = (q0 + 1) / 25, qp = (q0 + 1) - cc * 25;
                    y2h1[cc * 808 + qp * 32 + co] = (unsigned short)(hp >> 16);
                    y2l1[cc * 808 + qp * 32 + co] = (unsigned short)(lp >> 16);
                }
            }
        }
    }
    __syncthreads();

    // ---- conv3 MFMA 16x16x32: wave = Ntile, M rows = 10 chunks (5+5) ----
    {
        const uint4* w3f4 = (const uint4*)(wsu + OFF_W3F);
        f32x4 acc3 = {0.f, 0.f, 0.f, 0.f};
        for (int b5 = 0; b5 < 5; ++b5) {
            uint4 BH[5], BL[5];
            #pragma unroll
            for (int i = 0; i < 5; ++i) {
                int s = b5 * 5 + i;
                BH[i] = w3f4[((s * 4 + wid) * 2 + 0) * 64 + lane];
                BL[i] = w3f4[((s * 4 + wid) * 2 + 1) * 64 + lane];
            }
            #pragma unroll
            for (int i = 0; i < 5; ++i) {
                int s = b5 * 5 + i;
                bf16x8 ah = {}, al = {};
                if (li < 5) {
                    if (li < tc0) {
                        ah = *(const bf16x8*)(y2h0 + li * 808 + s * 32 + lg * 8);
                        al = *(const bf16x8*)(y2l0 + li * 808 + s * 32 + lg * 8);
                    }
                } else if (li < 10) {
                    int c = li - 5;
                    if (c < tc1) {
                        ah = *(const bf16x8*)(y2h1 + c * 808 + s * 32 + lg * 8);
                        al = *(const bf16x8*)(y2l1 + c * 808 + s * 32 + lg * 8);
                    }
                }
                bf16x8 bh = *(const bf16x8*)&BH[i];
                bf16x8 bl = *(const bf16x8*)&BL[i];
                acc3 = __builtin_amdgcn_mfma_f32_16x16x32_bf16(ah, bh, acc3, 0, 0, 0);
                acc3 = __builtin_amdgcn_mfma_f32_16x16x32_bf16(al, bh, acc3, 0, 0, 0);
                acc3 = __builtin_amdgcn_mfma_f32_16x16x32_bf16(ah, bl, acc3, 0, 0, 0);
            }
        }
        int co = wid * 16 + li;
        float A3 = A_s[48 + co], B3 = Bc_s[48 + co];
        unsigned int* featp = (unsigned int*)ws + OFF_FEAT;
        #pragma unroll
        for (int rg = 0; rg < 4; rg += 2) {
            float f0 = swishf(fmaf(acc3[rg],     A3, B3));
            float f1 = swishf(fmaf(acc3[rg + 1], A3, B3));
            unsigned int hp = pk2(f0, f1);
            unsigned int lp = pk2(f0 - bf16_tof((unsigned short)hp),
                                  f1 - bf16_tof((unsigned short)(hp >> 16)));
            unsigned int val0 = (hp & 0xFFFFu) | (lp << 16);
            unsigned int val1 = (hp >> 16) | (lp & 0xFFFF0000u);
            int cc0 = lg * 4 + rg;
            #pragma unroll
            for (int d = 0; d < 2; ++d) {
                int cc = cc0 + d;
                unsigned int val = d ? val1 : val0;
                if (cc < 5) {
                    if (cc < tc0)
                        featp[((size_t)(seq0 * NCHUNK + tile0 * 5 + cc)) * 64 + co] = val;
                } else if (cc < 10) {
                    int c = cc - 5;
                    if (c < tc1)
                        featp[((size_t)(seq1 * NCHUNK + tile1 * 5 + c)) * 64 + co] = val;
                }
            }
        }
    }
}

// One block per sequence; each WAVE owns 2 heads end-to-end, zero barriers in
// the head loop. LDS diet (38.8 KB -> 4 blocks/CU): f32F/wh_s/rowqc/abar moved
// to registers + shuffles / L2-direct; fred aliases dead f_p.
__global__ __launch_bounds__(256, 4) void mha_kernel(
    const float* __restrict__ ws, float* __restrict__ out, int B)
{
    __shared__ __align__(16) unsigned int smem[9928];
    unsigned int* f_p = smem;                         // [0,1496)  22x68 packed
    // per-wave T' planes: qh (u16, 22x68) at word 1496+w*1496, ql at +748 words
    // P per wave: (float*)(smem+7480) + w*484
    float* fbar_s = (float*)(smem + 9416);            // 512
    float* fred   = (float*)smem;                     // 256, ALIAS f_p (dead after loop)

    int t = threadIdx.x, b = blockIdx.x;
    int lane = t & 63, wid = t >> 6;
    int li = lane & 15, lg = lane >> 4;
    const unsigned int* wsu = (const unsigned int*)ws;
    const unsigned int* featp = wsu + OFF_FEAT + (size_t)b * 1408;
    for (int i = t; i < 1408; i += 256)
        f_p[(i >> 6) * 68 + (i & 63)] = featp[i];
    __syncthreads();

    unsigned short* qh_w = (unsigned short*)(smem + 1496 + wid * 1496);
    unsigned short* ql_w = qh_w + 1496;               // +748 u32
    float* P = (float*)(smem + 7480) + wid * 484;

    // rowqc in REGISTER: lane = hl*22+s (lanes>=44 hold harmless duplicates)
    float rowqv;
    {
        int hl = lane / 22; if (hl > 1) hl = 1;
        int s = lane - hl * 22; if (s > 21) s = 21;
        int h = wid * 2 + hl;
        float acc = ws[OFF_CH + h];
        const float* uh = ws + OFF_UH + h * 64;
        #pragma unroll 8
        for (int d = 0; d < 64; ++d)
            acc = fmaf(unpk_f32(f_p[s * 68 + d]), uh[d], acc);
        rowqv = acc;
    }

    // F A-frags (also the B-frags of F^T); rows>=22 read garbage -> unused D rows
    bf16x8 fah[2][2], fal[2][2];
    #pragma unroll
    for (int mt = 0; mt < 2; ++mt)
        #pragma unroll
        for (int ks = 0; ks < 2; ++ks)
            frag_from_packed(f_p + (mt * 16 + li) * 68 + ks * 32 + lg * 8,
                             fah[mt][ks], fal[mt][ks]);

    const uint4* mhf4 = (const uint4*)(wsu + OFF_MHF);

    #pragma unroll
    for (int hh = 0; hh < 2; ++hh) {
        int h = wid * 2 + hh;
        // ---- T' = F @ Mh : all 4 Ntiles in this wave ----
        f32x4 a0t0 = {0,0,0,0}, a0t1 = a0t0, a0t2 = a0t0, a0t3 = a0t0;
        f32x4 a1t0 = a0t0, a1t1 = a0t0, a1t2 = a0t0, a1t3 = a0t0;
        #pragma unroll
        for (int nt = 0; nt < 4; ++nt) {
            f32x4 r0 = {0,0,0,0}, r1 = {0,0,0,0};
            #pragma unroll
            for (int ks = 0; ks < 2; ++ks) {
                uint4 bh4 = mhf4[h * 1024 + ks * 512 + nt * 128 + lane];
                uint4 bl4 = mhf4[h * 1024 + ks * 512 + nt * 128 + 64 + lane];
                bf16x8 bh = *(const bf16x8*)&bh4;
                bf16x8 bl = *(const bf16x8*)&bl4;
                r0 = __builtin_amdgcn_mfma_f32_16x16x32_bf16(fah[0][ks], bh, r0, 0, 0, 0);
                r0 = __builtin_amdgcn_mfma_f32_16x16x32_bf16(fal[0][ks], bh, r0, 0, 0, 0);
                r0 = __builtin_amdgcn_mfma_f32_16x16x32_bf16(fah[0][ks], bl, r0, 0, 0, 0);
                r1 = __builtin_amdgcn_mfma_f32_16x16x32_bf16(fah[1][ks], bh, r1, 0, 0, 0);
                r1 = __builtin_amdgcn_mfma_f32_16x16x32_bf16(fal[1][ks], bh, r1, 0, 0, 0);
                r1 = __builtin_amdgcn_mfma_f32_16x16x32_bf16(fah[1][ks], bl, r1, 0, 0, 0);
            }
            if (nt == 0) { a0t0 = r0; a1t0 = r1; }
            else if (nt == 1) { a0t1 = r0; a1t1 = r1; }
            else if (nt == 2) { a0t2 = r0; a1t2 = r1; }
            else { a0t3 = r0; a1t3 = r1; }
        }
        // epilogue -> two u16 planes, paired cvt_pk; wh read L2-direct
        #pragma unroll
        for (int nt = 0; nt < 4; ++nt) {
            int col = nt * 16 + li;
            float wv = ws[OFF_WH + h * 64 + col];
            f32x4 r0 = (nt == 0) ? a0t0 : (nt == 1) ? a0t1 : (nt == 2) ? a0t2 : a0t3;
            f32x4 r1 = (nt == 0) ? a1t0 : (nt == 1) ? a1t1 : (nt == 2) ? a1t2 : a1t3;
            #pragma unroll
            for (int rg = 0; rg < 4; rg += 2) {
                int rowA = lg * 4 + rg;
                {
                    float v0 = r0[rg] + wv, v1 = r0[rg + 1] + wv;
                    unsigned int hp = pk2(v0, v1);
                    unsigned int lp = pk2(v0 - bf16_tof((unsigned short)hp),
                                          v1 - bf16_tof((unsigned short)(hp >> 16)));
                    qh_w[rowA * 68 + col] = (unsigned short)hp;
                    ql_w[rowA * 68 + col] = (unsigned short)lp;
                    qh_w[(rowA + 1) * 68 + col] = (unsigned short)(hp >> 16);
                    ql_w[(rowA + 1) * 68 + col] = (unsigned short)(lp >> 16);
                }
                int rowB = 16 + rowA;
                if (rowB < 22) {
                    float v0 = r1[rg] + wv, v1 = r1[rg + 1] + wv;
                    unsigned int hp = pk2(v0, v1);
                    unsigned int lp = pk2(v0 - bf16_tof((unsigned short)hp),
                                          v1 - bf16_tof((unsigned short)(hp >> 16)));
                    qh_w[rowB * 68 + col] = (unsigned short)hp;
                    ql_w[rowB * 68 + col] = (unsigned short)lp;
                    if (rowB + 1 < 22) {
                        qh_w[(rowB + 1) * 68 + col] = (unsigned short)(hp >> 16);
                        ql_w[(rowB + 1) * 68 + col] = (unsigned short)(lp >> 16);
                    }
                }
            }
        }
        // ---- S = T' @ F^T : 4 quadrants in this wave ----
        #pragma unroll
        for (int mt = 0; mt < 2; ++mt) {
            union { uint2 u[2]; bf16x8 v; } Th0, Tl0, Th1, Tl1;
            {
                const unsigned short* hp = qh_w + (mt * 16 + li) * 68 + lg * 8;
                const unsigned short* lp = ql_w + (mt * 16 + li) * 68 + lg * 8;
                Th0.u[0] = *(const uint2*)hp;        Th0.u[1] = *(const uint2*)(hp + 4);
                Tl0.u[0] = *(const uint2*)lp;        Tl0.u[1] = *(const uint2*)(lp + 4);
                Th1.u[0] = *(const uint2*)(hp + 32); Th1.u[1] = *(const uint2*)(hp + 36);
                Tl1.u[0] = *(const uint2*)(lp + 32); Tl1.u[1] = *(const uint2*)(lp + 36);
            }
            #pragma unroll
            for (int ntile = 0; ntile < 2; ++ntile) {
                f32x4 sacc = {0, 0, 0, 0};
                sacc = __builtin_amdgcn_mfma_f32_16x16x32_bf16(Th0.v, fah[ntile][0], sacc, 0, 0, 0);
                sacc = __builtin_amdgcn_mfma_f32_16x16x32_bf16(Tl0.v, fah[ntile][0], sacc, 0, 0, 0);
                sacc = __builtin_amdgcn_mfma_f32_16x16x32_bf16(Th0.v, fal[ntile][0], sacc, 0, 0, 0);
                sacc = __builtin_amdgcn_mfma_f32_16x16x32_bf16(Th1.v, fah[ntile][1], sacc, 0, 0, 0);
                sacc = __builtin_amdgcn_mfma_f32_16x16x32_bf16(Tl1.v, fah[ntile][1], sacc, 0, 0, 0);
                sacc = __builtin_amdgcn_mfma_f32_16x16x32_bf16(Th1.v, fal[ntile][1], sacc, 0, 0, 0);
                int u = ntile * 16 + li;
                #pragma unroll
                for (int r = 0; r < 4; ++r) {
                    int s = mt * 16 + lg * 4 + r;
                    float rq = __shfl(rowqv, hh * 22 + (s < 22 ? s : 0));
                    if (s < 22 && u < 22)
                        P[s * 22 + u] = sacc[r] + rq;
                }
            }
        }
        // ---- C: lane-parallel softmax + weighted colmean + fbar (shuffles) ----
        {
            int r2 = lane >> 1, c2 = lane & 1;
            float pm = -1e30f, psum = 0.f;
            if (lane < 44) {
                #pragma unroll
                for (int j = 0; j < 11; ++j) pm = fmaxf(pm, P[r2 * 22 + c2 * 11 + j]);
            }
            float m = fmaxf(__shfl(pm, 2 * lane), __shfl(pm, 2 * lane + 1)); // lane<22
            float rm = __shfl(m, r2);
            if (lane < 44) {
                #pragma unroll
                for (int j = 0; j < 11; ++j) {
                    int idx = r2 * 22 + c2 * 11 + j;
                    float ev = __expf(P[idx] - rm);
                    P[idx] = ev;
                    psum += ev;
                }
            }
            float sum = __shfl(psum, 2 * lane) + __shfl(psum, 2 * lane + 1);  // lane<22
            float rinv = 1.f / sum;                                           // lane<22
            float a = 0.f;
            #pragma unroll
            for (int s = 0; s < 22; ++s) {
                float rv = __shfl(rinv, s);
                if (lane < 22) a = fmaf(P[s * 22 + lane], rv, a);
            }
            float av = a * (1.f / 22.f);                                      // abar, lane<22
            float acc = 0.f;
            #pragma unroll
            for (int u = 0; u < 22; ++u) {
                float au = __shfl(av, u);
                acc = fmaf(au, unpk_f32(f_p[u * 68 + lane]), acc);
            }
            fbar_s[h * 64 + lane] = acc;
        }
    }
    __syncthreads();
    // out = cbias' + fbar(512) @ WC  (fred aliases dead f_p)
    {
        int d = t & 63, part = t >> 6;
        const float* wc = ws + OFF_WC;
        float acc = 0.f;
        for (int j = part * 128; j < part * 128 + 128; ++j)
            acc = fmaf(fbar_s[j], wc[j * 64 + d], acc);
        fred[part * 64 + d] = acc;
    }
    __syncthreads();
    if (t < 64)
        out[(size_t)b * 64 + t] = ws[OFF_CBIAS + t]
            + fred[t] + fred[64 + t] + fred[128 + t] + fred[192 + t];
}

extern "C" void kernel_launch(void* const* d_in, const int* in_sizes, int n_in,
                              void* d_out, int out_size, void* d_ws, size_t ws_size,
                              hipStream_t stream) {
    const float* audio1 = (const float*)d_in[0];
    const float* audio2 = (const float*)d_in[1];
    const float* w1   = (const float*)d_in[2];
    const float* b1   = (const float*)d_in[3];
    const float* g1   = (const float*)d_in[4];
    const float* be1  = (const float*)d_in[5];
    const float* m1   = (const float*)d_in[6];
    const float* v1   = (const float*)d_in[7];
    const float* w2   = (const float*)d_in[8];
    const float* b2   = (const float*)d_in[9];
    const float* g2   = (const float*)d_in[10];
    const float* be2  = (const float*)d_in[11];
    const float* m2   = (const float*)d_in[12];
    const float* v2   = (const float*)d_in[13];
    const float* w3   = (const float*)d_in[14];
    const float* b3   = (const float*)d_in[15];
    const float* g3   = (const float*)d_in[16];
    const float* be3  = (const float*)d_in[17];
    const float* m3   = (const float*)d_in[18];
    const float* v3   = (const float*)d_in[19];
    const float* Wq   = (const float*)d_in[20];
    const float* bq   = (const float*)d_in[21];
    const float* Wk   = (const float*)d_in[22];
    const float* bk   = (const float*)d_in[23];
    const float* Wv   = (const float*)d_in[24];
    const float* bv   = (const float*)d_in[25];
    const float* Wfc  = (const float*)d_in[26];
    const float* bfc  = (const float*)d_in[27];
    const float* Wout = (const float*)d_in[28];
    const float* bout = (const float*)d_in[29];

    float* ws  = (float*)d_ws;
    float* out = (float*)d_out;
    int B = in_sizes[0] / SEQLEN;   // 4096
    int nseq = 2 * B;
    int npair = nseq * 5 / 2;       // two tiles per block

    repack_kernel<<<(REPACK_N + 255) / 256, 256, 0, stream>>>(
        w1, w2, w3, Wq, Wk, Wv, Wfc, Wout, bq, bk, ws);
    repack2_kernel<<<128, 256, 0, stream>>>(Wv, ws);
    cbias_kernel<<<1, 64, 0, stream>>>(Wfc, Wout, bfc, bout, bv, ws);
    encoder_kernel<<<npair, 256, 0, stream>>>(audio1, audio2,
        b1, g1, be1, m1, v1,
        b2, g2, be2, m2, v2,
        b3, g3, be3, m3, v3,
        ws, B);
    mha_kernel<<<nseq, 256, 0, stream>>>(ws, out, B);
}

// Round 14
// 725.939 us; speedup vs baseline: 1.0412x; 1.0412x over previous
//
#include <hip/hip_runtime.h>
#include <hip/hip_bf16.h>
#include <math.h>

#define NCHUNK 22
#define SEQLEN 600
#define BN_EPS 1e-5f

// ws offsets (4-byte units)
#define OFF_W1F    0         // 1024   u32 : conv1 B dup-frags [ph2][pat2][lane][r]
#define OFF_W2F    1024      // 13312  u32 : conv2 32x32 B-frags [s26][hl2][lane][r4]
#define OFF_W3F    14336     // 51200  u32 : conv3 B-frags [s25][nt4][hl2][lane][r4]
#define OFF_MHF    65536     // 32768  u32 : Mh=WqT*Wk B-frags [h8][ks2][nt4][hl2][lane][r4]
#define OFF_WC     98304     // 32768  f32 : WC (final, by repack2)
#define OFF_UH     131072    // 512    f32 : u_h[h][d] = sum_e Wq[h,e,d]*bk[h,e]
#define OFF_WH     131584    // 512    f32 : w_h[h][d] = sum_e Wk[h,e,d]*bq[h,e]
#define OFF_CH     132096    // 8      f32 : c_h = bq.bk
#define OFF_CBIAS  132104    // 64     f32 : all-bias fold (cbias kernel)
#define OFF_WCOMB  132168    // 32768  f32 : Wcomb intermediate (repack)
#define OFF_FEAT   164936    // 2*B*22*64 u32 (PACKED hi|lo)
#define REPACK_N   132104

typedef short bf16x8 __attribute__((ext_vector_type(8)));
typedef float f32x4 __attribute__((ext_vector_type(4)));
typedef float f32x16 __attribute__((ext_vector_type(16)));

#if __has_builtin(__builtin_amdgcn_perm)
#define PERM_HI(r0, r1) __builtin_amdgcn_perm((r1), (r0), 0x05040100u)
#define PERM_LO(r0, r1) __builtin_amdgcn_perm((r1), (r0), 0x07060302u)
#else
#define PERM_HI(r0, r1) (((r0) & 0xFFFFu) | ((r1) << 16))
#define PERM_LO(r0, r1) (((r0) >> 16) | ((r1) & 0xFFFF0000u))
#endif

__device__ __forceinline__ float swishf(float z) {
    return z / (1.f + __expf(-z));
}
__device__ __forceinline__ unsigned short bf16_rne(float f) {
    __hip_bfloat16 h = __float2bfloat16(f);
    unsigned short u; __builtin_memcpy(&u, &h, 2); return u;
}
__device__ __forceinline__ float bf16_tof(unsigned short h) {
    return __uint_as_float(((unsigned int)h) << 16);
}
__device__ __forceinline__ unsigned int pk2(float f0, float f1) {
    __hip_bfloat162 b2;
    b2.x = __float2bfloat16(f0);
    b2.y = __float2bfloat16(f1);
    unsigned int r; __builtin_memcpy(&r, &b2, 4); return r;
}
__device__ __forceinline__ unsigned int pack_hl(float f) {
    unsigned short h = bf16_rne(f);
    unsigned short l = bf16_rne(f - bf16_tof(h));
    return (unsigned int)h | ((unsigned int)l << 16);
}
__device__ __forceinline__ float unpk_f32(unsigned int w) {
    return __uint_as_float(w << 16) + __uint_as_float(w & 0xFFFF0000u);
}
__device__ __forceinline__ unsigned int dup_word(float f, int pat) {
    unsigned short h = bf16_rne(f);
    unsigned short v = pat ? bf16_rne(f - bf16_tof(h)) : h;
    return (unsigned int)v | ((unsigned int)v << 16);
}
__device__ __forceinline__ unsigned int frag_word(float f0, float f1, int hl) {
    unsigned short h0 = bf16_rne(f0), h1 = bf16_rne(f1);
    if (hl == 0) return (unsigned int)h0 | ((unsigned int)h1 << 16);
    unsigned short l0 = bf16_rne(f0 - bf16_tof(h0));
    unsigned short l1 = bf16_rne(f1 - bf16_tof(h1));
    return (unsigned int)l0 | ((unsigned int)l1 << 16);
}
__device__ __forceinline__ void frag_from_packed(const unsigned int* p, bf16x8& h8, bf16x8& l8) {
    unsigned int r0 = p[0], r1 = p[1], r2 = p[2], r3 = p[3];
    unsigned int r4 = p[4], r5 = p[5], r6 = p[6], r7 = p[7];
    union U { unsigned int w[4]; bf16x8 v; } H, L;
    H.w[0] = PERM_HI(r0, r1); H.w[1] = PERM_HI(r2, r3);
    H.w[2] = PERM_HI(r4, r5); H.w[3] = PERM_HI(r6, r7);
    L.w[0] = PERM_LO(r0, r1); L.w[1] = PERM_LO(r2, r3);
    L.w[2] = PERM_LO(r4, r5); L.w[3] = PERM_LO(r6, r7);
    h8 = H.v; l8 = L.v;
}

__global__ __launch_bounds__(256) void repack_kernel(
    const float* __restrict__ w1, const float* __restrict__ w2, const float* __restrict__ w3,
    const float* __restrict__ Wq, const float* __restrict__ Wk, const float* __restrict__ Wv,
    const float* __restrict__ Wfc, const float* __restrict__ Wout,
    const float* __restrict__ bq, const float* __restrict__ bk,
    float* __restrict__ ws)
{
    int tid = blockIdx.x * 256 + threadIdx.x;
    unsigned int* wsu = (unsigned int*)ws;
    if (tid < 1024) {                        // conv1 dup-B
        int r = tid & 3, lane = (tid >> 2) & 63, pat = (tid >> 8) & 1, ph = (tid >> 9) & 1;
        int li = lane & 15, lg = lane >> 4;
        int k = ph * 16 + lg * 4 + r;
        float f = (k < 26) ? w1[li * 26 + k] : 0.f;
        wsu[OFF_W1F + tid] = dup_word(f, pat);
    }
    int t2 = tid - 1024;
    if (t2 >= 0 && t2 < 13312) {             // conv2 32x32x16 B-frags
        int r = t2 & 3, lane = (t2 >> 2) & 63, hl = (t2 >> 8) & 1, s = t2 >> 9;
        int co = lane & 31;
        int ci0 = (lane >> 5) * 8;
        float f0 = w2[co * 416 + (ci0 + 2 * r) * 26 + s];
        float f1 = w2[co * 416 + (ci0 + 2 * r + 1) * 26 + s];
        wsu[OFF_W2F + t2] = frag_word(f0, f1, hl);
    }
    int t3 = tid - 14336;
    if (t3 >= 0 && t3 < 51200) {             // conv3 B-frags
        int r = t3 & 3, l = (t3 >> 2) & 63, hl = (t3 >> 8) & 1;
        int nt = (t3 >> 9) & 3, s = t3 >> 11;
        int co = nt * 16 + (l & 15);
        int k0 = s * 32 + (l >> 4) * 8 + 2 * r;
        float f0 = w3[co * 800 + (k0 & 31) * 25 + (k0 >> 5)];
        float f1 = w3[co * 800 + ((k0 + 1) & 31) * 25 + ((k0 + 1) >> 5)];
        wsu[OFF_W3F + t3] = frag_word(f0, f1, hl);
    }
    int t4 = tid - 65536;
    if (t4 >= 0 && t4 < 32768) {             // Mh B-frags
        int r = t4 & 3, l = (t4 >> 2) & 63, hl = (t4 >> 8) & 1;
        int nt = (t4 >> 9) & 3, ks = (t4 >> 11) & 1, h = t4 >> 12;
        int n = nt * 16 + (l & 15);
        int d0 = ks * 32 + (l >> 4) * 8 + 2 * r;
        const float* wqh = Wq + h * 4096;
        const float* wkh = Wk + h * 4096;
        float f0 = 0.f, f1 = 0.f;
        #pragma unroll 8
        for (int e = 0; e < 64; ++e) {
            float wk_en = wkh[e * 64 + n];
            f0 = fmaf(wqh[e * 64 + d0],     wk_en, f0);
            f1 = fmaf(wqh[e * 64 + d0 + 1], wk_en, f1);
        }
        wsu[OFF_MHF + t4] = frag_word(f0, f1, hl);
    }
    int t7 = tid - 98304;
    if (t7 >= 0 && t7 < 32768) {             // Wcomb[j][k] intermediate
        int k = t7 & 63, j = t7 >> 6;
        float acc = 0.f;
        #pragma unroll 8
        for (int d = 0; d < 64; ++d)
            acc = fmaf(Wfc[d * 512 + j], Wout[k * 64 + d], acc);
        ws[OFF_WCOMB + t7] = acc;
    }
    int t8 = tid - 131072;
    if (t8 >= 0 && t8 < 512) {               // u_h
        int h = t8 >> 6, d = t8 & 63;
        float acc = 0.f;
        #pragma unroll 8
        for (int e = 0; e < 64; ++e) acc = fmaf(Wq[h * 4096 + e * 64 + d], bk[h * 64 + e], acc);
        ws[OFF_UH + t8] = acc;
    }
    int t9 = tid - 131584;
    if (t9 >= 0 && t9 < 512) {               // w_h
        int h = t9 >> 6, d = t9 & 63;
        float acc = 0.f;
        #pragma unroll 8
        for (int e = 0; e < 64; ++e) acc = fmaf(Wk[h * 4096 + e * 64 + d], bq[h * 64 + e], acc);
        ws[OFF_WH + t9] = acc;
    }
    int t10 = tid - 132096;
    if (t10 >= 0 && t10 < 8) {               // c_h
        float acc = 0.f;
        #pragma unroll 8
        for (int e = 0; e < 64; ++e) acc = fmaf(bq[t10 * 64 + e], bk[t10 * 64 + e], acc);
        ws[OFF_CH + t10] = acc;
    }
}

// WC[h*64+d][k] = sum_e Wv[h,e,d] * Wcomb[(h*64+e)][k]
__global__ __launch_bounds__(256) void repack2_kernel(
    const float* __restrict__ Wv, float* __restrict__ ws)
{
    int tid = blockIdx.x * 256 + threadIdx.x;   // 32768
    int k = tid & 63, j = tid >> 6;
    int h = j >> 6, d = j & 63;
    const float* wcomb = ws + OFF_WCOMB + (size_t)(h * 64) * 64 + k;
    const float* wv = Wv + h * 4096 + d;
    float acc = 0.f;
    #pragma unroll 8
    for (int e = 0; e < 64; ++e)
        acc = fmaf(wv[e * 64], wcomb[e * 64], acc);
    ws[OFF_WC + tid] = acc;
}

// cbias'[k] = bout[k] + sum_dp (bfc[dp] + sum_j bv[j]*Wfc[dp][j]) * Wout[k][dp]
__global__ __launch_bounds__(64) void cbias_kernel(
    const float* __restrict__ Wfc, const float* __restrict__ Wout,
    const float* __restrict__ bfc, const float* __restrict__ bout,
    const float* __restrict__ bv, float* __restrict__ ws)
{
    __shared__ float sd_s[64];
    int t = threadIdx.x;
    float acc = 0.f;
    for (int j = 0; j < 512; ++j) acc = fmaf(bv[j], Wfc[t * 512 + j], acc);
    sd_s[t] = acc;
    __syncthreads();
    float cb = bout[t];
    #pragma unroll 8
    for (int dp = 0; dp < 64; ++dp) cb = fmaf(bfc[dp] + sd_s[dp], Wout[t * 64 + dp], cb);
    ws[OFF_CBIAS + t] = cb;
}

// Encoder: THREE tiles per block. conv2 stages B once for 3 acc chains; conv3
// packs 15 chunks into one 16-row Mtile (w3 stream serves 3 tiles). y2 aliases
// the dead a_p/w2f/y1 region. LDS 49.4 KB -> 3 blocks/CU. Tail block guarded
// with tc=0 (no stores, clamped loads).
__global__ __launch_bounds__(256, 3) void encoder_kernel(
    const float* __restrict__ audio1, const float* __restrict__ audio2,
    const float* __restrict__ b1, const float* __restrict__ g1, const float* __restrict__ be1,
    const float* __restrict__ m1, const float* __restrict__ v1,
    const float* __restrict__ b2, const float* __restrict__ g2, const float* __restrict__ be2,
    const float* __restrict__ m2, const float* __restrict__ v2,
    const float* __restrict__ b3, const float* __restrict__ g3, const float* __restrict__ be3,
    const float* __restrict__ m3, const float* __restrict__ v3,
    float* __restrict__ ws, int B)
{
    __shared__ __align__(16) unsigned int smem[12344];
    float* A_s  = (float*)smem;                              // [0,112)
    float* Bc_s = (float*)(smem + 112);                      // [112,224)
    unsigned int* a_p0 = smem + 224;                         // [224,416)
    unsigned int* a_p1 = smem + 416;                         // [416,608)
    unsigned int* a_p2 = smem + 608;                         // [608,800)
    unsigned int* w2f  = smem + 800;                         // [800,2848) 2x1024 dbuf
    unsigned short* y1h0 = (unsigned short*)(smem + 2848);   // 154x20 u16 (1540 u32)
    unsigned short* y1l0 = (unsigned short*)(smem + 4388);
    unsigned short* y1h1 = (unsigned short*)(smem + 5928);
    unsigned short* y1l1 = (unsigned short*)(smem + 7468);
    unsigned short* y1h2 = (unsigned short*)(smem + 9008);
    unsigned short* y1l2 = (unsigned short*)(smem + 10548);  // ends 12088
    // y2 aliases [224,12344): a_p + w2f + y1 all dead when written
    unsigned short* y2h0 = (unsigned short*)(smem + 224);    // 5x808 u16 (2020 u32)
    unsigned short* y2l0 = (unsigned short*)(smem + 2244);
    unsigned short* y2h1 = (unsigned short*)(smem + 4264);
    unsigned short* y2l1 = (unsigned short*)(smem + 6284);
    unsigned short* y2h2 = (unsigned short*)(smem + 8304);
    unsigned short* y2l2 = (unsigned short*)(smem + 10324);  // ends 12344

    int t = threadIdx.x;
    int blk = blockIdx.x;
    int ntile = 10 * B;                     // nseq * 5
    int g0 = blk * 3, g1v = g0 + 1, g2v = g0 + 2;
    bool v1ok = g1v < ntile, v2ok = g2v < ntile;
    int gc1 = v1ok ? g1v : 0, gc2 = v2ok ? g2v : 0;
    int seq0 = g0 / 5,  tile0 = g0 - seq0 * 5;
    int seq1 = gc1 / 5, tile1 = gc1 - seq1 * 5;
    int seq2 = gc2 / 5, tile2 = gc2 - seq2 * 5;
    int tc0 = (tile0 == 4) ? 2 : 5;
    int tc1 = v1ok ? ((tile1 == 4) ? 2 : 5) : 0;
    int tc2 = v2ok ? ((tile2 == 4) ? 2 : 5) : 0;
    int nq0 = 25 * tc0, nq1 = 25 * tc1, nq2 = 25 * tc2;
    int ny10 = nq0 + 25, ny11 = nq1 + 25, ny12 = nq2 + 25;
    int na0 = nq0 + 50, na1 = nq1 + 50, na2 = nq2 + 50;
    const unsigned int* wsu = (const unsigned int*)ws;
    int lane = t & 63, wid = t >> 6;
    int li = lane & 15, lg = lane >> 4;

    const float* aud0 = (seq0 < B ? audio1 + (size_t)seq0 * SEQLEN
                                  : audio2 + (size_t)(seq0 - B) * SEQLEN) + tile0 * 125;
    const float* aud1 = (seq1 < B ? audio1 + (size_t)seq1 * SEQLEN
                                  : audio2 + (size_t)(seq1 - B) * SEQLEN) + tile1 * 125;
    const float* aud2 = (seq2 < B ? audio1 + (size_t)seq2 * SEQLEN
                                  : audio2 + (size_t)(seq2 - B) * SEQLEN) + tile2 * 125;
    uint4 w1b[2][2];
    #pragma unroll
    for (int ph = 0; ph < 2; ++ph)
        #pragma unroll
        for (int pat = 0; pat < 2; ++pat)
            w1b[ph][pat] = *(const uint4*)(wsu + OFF_W1F + ((ph * 2 + pat) * 64 + lane) * 4);

    if (t < 192) {
        a_p0[t] = (t < na0) ? pack_hl(aud0[t]) : 0u;
        a_p1[t] = (t < na1) ? pack_hl(aud1[t]) : 0u;
        a_p2[t] = (t < na2) ? pack_hl(aud2[t]) : 0u;
    }
    *(uint4*)(w2f + t * 4) = *(const uint4*)(wsu + OFF_W2F + t * 4);   // stage 0
    if (t < 16)       { float A = g1[t] * rsqrtf(v1[t] + BN_EPS); A_s[t] = A; Bc_s[t] = (b1[t] - m1[t]) * A + be1[t]; }
    else if (t < 48)  { int i = t - 16; float A = g2[i] * rsqrtf(v2[i] + BN_EPS); A_s[t] = A; Bc_s[t] = (b2[i] - m2[i]) * A + be2[i]; }
    else if (t < 112) { int i = t - 48; float A = g3[i] * rsqrtf(v3[i] + BN_EPS); A_s[t] = A; Bc_s[t] = (b3[i] - m3[i]) * A + be3[i]; }
    // zero y1 tail rows (p >= ny1) for all tiles
    for (int i = ny10 * 10 + t; i < 1540; i += 256) {
        (smem + 2848)[i] = 0u; (smem + 4388)[i] = 0u;
    }
    for (int i = ny11 * 10 + t; i < 1540; i += 256) {
        (smem + 5928)[i] = 0u; (smem + 7468)[i] = 0u;
    }
    for (int i = ny12 * 10 + t; i < 1540; i += 256) {
        (smem + 9008)[i] = 0u; (smem + 10548)[i] = 0u;
    }
    __syncthreads();

    // ---- conv1 MFMA (dup-B) x3 tiles ----
    {
        float Ai = A_s[li], Bi = Bc_s[li];
        #pragma unroll
        for (int tl = 0; tl < 3; ++tl) {
            const unsigned int* ap_base = (tl == 0) ? a_p0 : (tl == 1) ? a_p1 : a_p2;
            unsigned short* yh = (tl == 0) ? y1h0 : (tl == 1) ? y1h1 : y1h2;
            unsigned short* yl = (tl == 0) ? y1l0 : (tl == 1) ? y1l1 : y1l2;
            int ny1 = (tl == 0) ? ny10 : (tl == 1) ? ny11 : ny12;
            int nMt1 = (ny1 + 15) >> 4;
            for (int mt = wid; mt < nMt1; mt += 4) {
                f32x4 acc = {0.f, 0.f, 0.f, 0.f};
                #pragma unroll
                for (int ph = 0; ph < 2; ++ph) {
                    const unsigned int* ap = ap_base + mt * 16 + li + ph * 16 + lg * 4;
                    union { unsigned int w[4]; bf16x8 v; } A;
                    A.w[0] = ap[0]; A.w[1] = ap[1]; A.w[2] = ap[2]; A.w[3] = ap[3];
                    bf16x8 b0 = *(const bf16x8*)&w1b[ph][0];
                    bf16x8 b1 = *(const bf16x8*)&w1b[ph][1];
                    acc = __builtin_amdgcn_mfma_f32_16x16x32_bf16(A.v, b0, acc, 0, 0, 0);
                    acc = __builtin_amdgcn_mfma_f32_16x16x32_bf16(A.v, b1, acc, 0, 0, 0);
                }
                int p0 = mt * 16 + lg * 4;
                #pragma unroll
                for (int rg = 0; rg < 4; rg += 2) {
                    float f0 = swishf(fmaf(acc[rg],     Ai, Bi));
                    float f1 = swishf(fmaf(acc[rg + 1], Ai, Bi));
                    unsigned int hp = pk2(f0, f1);
                    unsigned int lp = pk2(f0 - bf16_tof((unsigned short)hp),
                                          f1 - bf16_tof((unsigned short)(hp >> 16)));
                    int p = p0 + rg;
                    if (p < ny1) {
                        yh[p * 20 + li] = (unsigned short)hp;
                        yl[p * 20 + li] = (unsigned short)lp;
                    }
                    if (p + 1 < ny1) {
                        yh[(p + 1) * 20 + li] = (unsigned short)(hp >> 16);
                        yl[(p + 1) * 20 + li] = (unsigned short)(lp >> 16);
                    }
                }
            }
        }
    }
    __syncthreads();

    // ---- conv2 MFMA 32x32x16: 3 tiles per stage (3 acc chains) ----
    int row0 = wid * 32 + (lane & 31);
    int ci0 = (lane >> 5) * 8;
    f32x16 accA, accB, accC;
    #pragma unroll
    for (int r = 0; r < 16; ++r) { accA[r] = 0.f; accB[r] = 0.f; accC[r] = 0.f; }

    for (int stg = 0; stg < 13; ++stg) {
        uint4 vnext;
        if (stg < 12)
            vnext = *(const uint4*)(wsu + OFF_W2F + (stg + 1) * 1024 + t * 4);
        const unsigned int* cur = w2f + (stg & 1) * 1024;
        #pragma unroll
        for (int half = 0; half < 2; ++half) {
            int s = stg * 2 + half;
            bf16x8 bh = *(const bf16x8*)(cur + half * 512 + lane * 4);
            bf16x8 bl = *(const bf16x8*)(cur + half * 512 + 256 + lane * 4);
            {   // tile 0
                const unsigned short* hp = y1h0 + (row0 + s) * 20 + ci0;
                const unsigned short* lp = y1l0 + (row0 + s) * 20 + ci0;
                union { uint2 u[2]; bf16x8 v; } Ah, Al;
                Ah.u[0] = *(const uint2*)hp; Ah.u[1] = *(const uint2*)(hp + 4);
                Al.u[0] = *(const uint2*)lp; Al.u[1] = *(const uint2*)(lp + 4);
                accA = __builtin_amdgcn_mfma_f32_32x32x16_bf16(Ah.v, bh, accA, 0, 0, 0);
                accA = __builtin_amdgcn_mfma_f32_32x32x16_bf16(Al.v, bh, accA, 0, 0, 0);
                accA = __builtin_amdgcn_mfma_f32_32x32x16_bf16(Ah.v, bl, accA, 0, 0, 0);
            }
            {   // tile 1
                const unsigned short* hp = y1h1 + (row0 + s) * 20 + ci0;
                const unsigned short* lp = y1l1 + (row0 + s) * 20 + ci0;
                union { uint2 u[2]; bf16x8 v; } Ah, Al;
                Ah.u[0] = *(const uint2*)hp; Ah.u[1] = *(const uint2*)(hp + 4);
                Al.u[0] = *(const uint2*)lp; Al.u[1] = *(const uint2*)(lp + 4);
                accB = __builtin_amdgcn_mfma_f32_32x32x16_bf16(Ah.v, bh, accB, 0, 0, 0);
                accB = __builtin_amdgcn_mfma_f32_32x32x16_bf16(Al.v, bh, accB, 0, 0, 0);
                accB = __builtin_amdgcn_mfma_f32_32x32x16_bf16(Ah.v, bl, accB, 0, 0, 0);
            }
            {   // tile 2
                const unsigned short* hp = y1h2 + (row0 + s) * 20 + ci0;
                const unsigned short* lp = y1l2 + (row0 + s) * 20 + ci0;
                union { uint2 u[2]; bf16x8 v; } Ah, Al;
                Ah.u[0] = *(const uint2*)hp; Ah.u[1] = *(const uint2*)(hp + 4);
                Al.u[0] = *(const uint2*)lp; Al.u[1] = *(const uint2*)(lp + 4);
                accC = __builtin_amdgcn_mfma_f32_32x32x16_bf16(Ah.v, bh, accC, 0, 0, 0);
                accC = __builtin_amdgcn_mfma_f32_32x32x16_bf16(Al.v, bh, accC, 0, 0, 0);
                accC = __builtin_amdgcn_mfma_f32_32x32x16_bf16(Ah.v, bl, accC, 0, 0, 0);
            }
        }
        if (stg < 12)
            *(uint4*)(w2f + ((stg + 1) & 1) * 1024 + t * 4) = vnext;
        __syncthreads();
    }
    // epilogue: y2 for 3 tiles, paired cvt_pk (aliases a_p+w2f+y1)
    {
        int co = lane & 31;
        float Ac = A_s[16 + co], Bc = Bc_s[16 + co];
        int rbase = 4 * (lane >> 5) + wid * 32;
        #pragma unroll
        for (int rg = 0; rg < 16; rg += 2) {
            int q0 = rbase + (rg & 3) + 8 * (rg >> 2);
            {   // tile 0
                float f0 = swishf(fmaf(accA[rg],     Ac, Bc));
                float f1 = swishf(fmaf(accA[rg + 1], Ac, Bc));
                unsigned int hp = pk2(f0, f1);
                unsigned int lp = pk2(f0 - bf16_tof((unsigned short)hp),
                                      f1 - bf16_tof((unsigned short)(hp >> 16)));
                if (q0 < nq0) {
                    int cc = q0 / 25, qp = q0 - cc * 25;
                    y2h0[cc * 808 + qp * 32 + co] = (unsigned short)hp;
                    y2l0[cc * 808 + qp * 32 + co] = (unsigned short)lp;
                }
                if (q0 + 1 < nq0) {
                    int cc = (q0 + 1) / 25, qp = (q0 + 1) - cc * 25;
                    y2h0[cc * 808 + qp * 32 + co] = (unsigned short)(hp >> 16);
                    y2l0[cc * 808 + qp * 32 + co] = (unsigned short)(lp >> 16);
                }
            }
            {   // tile 1
                float f0 = swishf(fmaf(accB[rg],     Ac, Bc));
                float f1 = swishf(fmaf(accB[rg + 1], Ac, Bc));
                unsigned int hp = pk2(f0, f1);
                unsigned int lp = pk2(f0 - bf16_tof((unsigned short)hp),
                                      f1 - bf16_tof((unsigned short)(hp >> 16)));
                if (q0 < nq1) {
                    int cc = q0 / 25, qp = q0 - cc * 25;
                    y2h1[cc * 808 + qp * 32 + co] = (unsigned short)hp;
                    y2l1[cc * 808 + qp * 32 + co] = (unsigned short)lp;
                }
                if (q0 + 1 < nq1) {
                    int cc = (q0 + 1) / 25, qp = (q0 + 1) - cc * 25;
                    y2h1[cc * 808 + qp * 32 + co] = (unsigned short)(hp >> 16);
                    y2l1[cc * 808 + qp * 32 + co] = (unsigned short)(lp >> 16);
                }
            }
            {   // tile 2
                float f0 = swishf(fmaf(accC[rg],     Ac, Bc));
                float f1 = swishf(fmaf(accC[rg + 1], Ac, Bc));
                unsigned int hp = pk2(f0, f1);
                unsigned int lp = pk2(f0 - bf16_tof((unsigned short)hp),
                                      f1 - bf16_tof((unsigned short)(hp >> 16)));
                if (q0 < nq2) {
                    int cc = q0 / 25, qp = q0 - cc * 25;
                    y2h2[cc * 808 + qp * 32 + co] = (unsigned short)hp;
                    y2l2[cc * 808 + qp * 32 + co] = (unsigned short)lp;
                }
                if (q0 + 1 < nq2) {
                    int cc = (q0 + 1) / 25, qp = (q0 + 1) - cc * 25;
                    y2h2[cc * 808 + qp * 32 + co] = (unsigned short)(hp >> 16);
                    y2l2[cc * 808 + qp * 32 + co] = (unsigned short)(lp >> 16);
                }
            }
        }
    }
    __syncthreads();

    // ---- conv3 MFMA 16x16x32: wave = Ntile, M rows = 15 chunks (5+5+5) ----
    {
        const uint4* w3f4 = (const uint4*)(wsu + OFF_W3F);
        f32x4 acc3 = {0.f, 0.f, 0.f, 0.f};
        for (int b5 = 0; b5 < 5; ++b5) {
            uint4 BH[5], BL[5];
            #pragma unroll
            for (int i = 0; i < 5; ++i) {
                int s = b5 * 5 + i;
                BH[i] = w3f4[((s * 4 + wid) * 2 + 0) * 64 + lane];
                BL[i] = w3f4[((s * 4 + wid) * 2 + 1) * 64 + lane];
            }
            #pragma unroll
            for (int i = 0; i < 5; ++i) {
                int s = b5 * 5 + i;
                bf16x8 ah = {}, al = {};
                if (li < 5) {
                    if (li < tc0) {
                        ah = *(const bf16x8*)(y2h0 + li * 808 + s * 32 + lg * 8);
                        al = *(const bf16x8*)(y2l0 + li * 808 + s * 32 + lg * 8);
                    }
                } else if (li < 10) {
                    int c = li - 5;
                    if (c < tc1) {
                        ah = *(const bf16x8*)(y2h1 + c * 808 + s * 32 + lg * 8);
                        al = *(const bf16x8*)(y2l1 + c * 808 + s * 32 + lg * 8);
                    }
                } else if (li < 15) {
                    int c = li - 10;
                    if (c < tc2) {
                        ah = *(const bf16x8*)(y2h2 + c * 808 + s * 32 + lg * 8);
                        al = *(const bf16x8*)(y2l2 + c * 808 + s * 32 + lg * 8);
                    }
                }
                bf16x8 bh = *(const bf16x8*)&BH[i];
                bf16x8 bl = *(const bf16x8*)&BL[i];
                acc3 = __builtin_amdgcn_mfma_f32_16x16x32_bf16(ah, bh, acc3, 0, 0, 0);
                acc3 = __builtin_amdgcn_mfma_f32_16x16x32_bf16(al, bh, acc3, 0, 0, 0);
                acc3 = __builtin_amdgcn_mfma_f32_16x16x32_bf16(ah, bl, acc3, 0, 0, 0);
            }
        }
        int co = wid * 16 + li;
        float A3 = A_s[48 + co], B3 = Bc_s[48 + co];
        unsigned int* featp = (unsigned int*)ws + OFF_FEAT;
        #pragma unroll
        for (int rg = 0; rg < 4; rg += 2) {
            float f0 = swishf(fmaf(acc3[rg],     A3, B3));
            float f1 = swishf(fmaf(acc3[rg + 1], A3, B3));
            unsigned int hp = pk2(f0, f1);
            unsigned int lp = pk2(f0 - bf16_tof((unsigned short)hp),
                                  f1 - bf16_tof((unsigned short)(hp >> 16)));
            unsigned int val0 = (hp & 0xFFFFu) | (lp << 16);
            unsigned int val1 = (hp >> 16) | (lp & 0xFFFF0000u);
            int cc0 = lg * 4 + rg;
            #pragma unroll
            for (int d = 0; d < 2; ++d) {
                int cc = cc0 + d;
                unsigned int val = d ? val1 : val0;
                if (cc < 5) {
                    if (cc < tc0)
                        featp[((size_t)(seq0 * NCHUNK + tile0 * 5 + cc)) * 64 + co] = val;
                } else if (cc < 10) {
                    int c = cc - 5;
                    if (c < tc1)
                        featp[((size_t)(seq1 * NCHUNK + tile1 * 5 + c)) * 64 + co] = val;
                } else if (cc < 15) {
                    int c = cc - 10;
                    if (c < tc2)
                        featp[((size_t)(seq2 * NCHUNK + tile2 * 5 + c)) * 64 + co] = val;
                }
            }
        }
    }
}

// One block per sequence; each WAVE owns 2 heads end-to-end, zero barriers in
// the head loop (R13 version).
__global__ __launch_bounds__(256, 4) void mha_kernel(
    const float* __restrict__ ws, float* __restrict__ out, int B)
{
    __shared__ __align__(16) unsigned int smem[9928];
    unsigned int* f_p = smem;                         // [0,1496)  22x68 packed
    float* fbar_s = (float*)(smem + 9416);            // 512
    float* fred   = (float*)smem;                     // 256, ALIAS f_p (dead after loop)

    int t = threadIdx.x, b = blockIdx.x;
    int lane = t & 63, wid = t >> 6;
    int li = lane & 15, lg = lane >> 4;
    const unsigned int* wsu = (const unsigned int*)ws;
    const unsigned int* featp = wsu + OFF_FEAT + (size_t)b * 1408;
    for (int i = t; i < 1408; i += 256)
        f_p[(i >> 6) * 68 + (i & 63)] = featp[i];
    __syncthreads();

    unsigned short* qh_w = (unsigned short*)(smem + 1496 + wid * 1496);
    unsigned short* ql_w = qh_w + 1496;               // +748 u32
    float* P = (float*)(smem + 7480) + wid * 484;

    // rowqc in REGISTER: lane = hl*22+s (lanes>=44 hold harmless duplicates)
    float rowqv;
    {
        int hl = lane / 22; if (hl > 1) hl = 1;
        int s = lane - hl * 22; if (s > 21) s = 21;
        int h = wid * 2 + hl;
        float acc = ws[OFF_CH + h];
        const float* uh = ws + OFF_UH + h * 64;
        #pragma unroll 8
        for (int d = 0; d < 64; ++d)
            acc = fmaf(unpk_f32(f_p[s * 68 + d]), uh[d], acc);
        rowqv = acc;
    }

    bf16x8 fah[2][2], fal[2][2];
    #pragma unroll
    for (int mt = 0; mt < 2; ++mt)
        #pragma unroll
        for (int ks = 0; ks < 2; ++ks)
            frag_from_packed(f_p + (mt * 16 + li) * 68 + ks * 32 + lg * 8,
                             fah[mt][ks], fal[mt][ks]);

    const uint4* mhf4 = (const uint4*)(wsu + OFF_MHF);

    #pragma unroll
    for (int hh = 0; hh < 2; ++hh) {
        int h = wid * 2 + hh;
        f32x4 a0t0 = {0,0,0,0}, a0t1 = a0t0, a0t2 = a0t0, a0t3 = a0t0;
        f32x4 a1t0 = a0t0, a1t1 = a0t0, a1t2 = a0t0, a1t3 = a0t0;
        #pragma unroll
        for (int nt = 0; nt < 4; ++nt) {
            f32x4 r0 = {0,0,0,0}, r1 = {0,0,0,0};
            #pragma unroll
            for (int ks = 0; ks < 2; ++ks) {
                uint4 bh4 = mhf4[h * 1024 + ks * 512 + nt * 128 + lane];
                uint4 bl4 = mhf4[h * 1024 + ks * 512 + nt * 128 + 64 + lane];
                bf16x8 bh = *(const bf16x8*)&bh4;
                bf16x8 bl = *(const bf16x8*)&bl4;
                r0 = __builtin_amdgcn_mfma_f32_16x16x32_bf16(fah[0][ks], bh, r0, 0, 0, 0);
                r0 = __builtin_amdgcn_mfma_f32_16x16x32_bf16(fal[0][ks], bh, r0, 0, 0, 0);
                r0 = __builtin_amdgcn_mfma_f32_16x16x32_bf16(fah[0][ks], bl, r0, 0, 0, 0);
                r1 = __builtin_amdgcn_mfma_f32_16x16x32_bf16(fah[1][ks], bh, r1, 0, 0, 0);
                r1 = __builtin_amdgcn_mfma_f32_16x16x32_bf16(fal[1][ks], bh, r1, 0, 0, 0);
                r1 = __builtin_amdgcn_mfma_f32_16x16x32_bf16(fah[1][ks], bl, r1, 0, 0, 0);
            }
            if (nt == 0) { a0t0 = r0; a1t0 = r1; }
            else if (nt == 1) { a0t1 = r0; a1t1 = r1; }
            else if (nt == 2) { a0t2 = r0; a1t2 = r1; }
            else { a0t3 = r0; a1t3 = r1; }
        }
        #pragma unroll
        for (int nt = 0; nt < 4; ++nt) {
            int col = nt * 16 + li;
            float wv = ws[OFF_WH + h * 64 + col];
            f32x4 r0 = (nt == 0) ? a0t0 : (nt == 1) ? a0t1 : (nt == 2) ? a0t2 : a0t3;
            f32x4 r1 = (nt == 0) ? a1t0 : (nt == 1) ? a1t1 : (nt == 2) ? a1t2 : a1t3;
            #pragma unroll
            for (int rg = 0; rg < 4; rg += 2) {
                int rowA = lg * 4 + rg;
                {
                    float v0 = r0[rg] + wv, v1 = r0[rg + 1] + wv;
                    unsigned int hp = pk2(v0, v1);
                    unsigned int lp = pk2(v0 - bf16_tof((unsigned short)hp),
                                          v1 - bf16_tof((unsigned short)(hp >> 16)));
                    qh_w[rowA * 68 + col] = (unsigned short)hp;
                    ql_w[rowA * 68 + col] = (unsigned short)lp;
                    qh_w[(rowA + 1) * 68 + col] = (unsigned short)(hp >> 16);
                    ql_w[(rowA + 1) * 68 + col] = (unsigned short)(lp >> 16);
                }
                int rowB = 16 + rowA;
                if (rowB < 22) {
                    float v0 = r1[rg] + wv, v1 = r1[rg + 1] + wv;
                    unsigned int hp = pk2(v0, v1);
                    unsigned int lp = pk2(v0 - bf16_tof((unsigned short)hp),
                                          v1 - bf16_tof((unsigned short)(hp >> 16)));
                    qh_w[rowB * 68 + col] = (unsigned short)hp;
                    ql_w[rowB * 68 + col] = (unsigned short)lp;
                    if (rowB + 1 < 22) {
                        qh_w[(rowB + 1) * 68 + col] = (unsigned short)(hp >> 16);
                        ql_w[(rowB + 1) * 68 + col] = (unsigned short)(lp >> 16);
                    }
                }
            }
        }
        #pragma unroll
        for (int mt = 0; mt < 2; ++mt) {
            union { uint2 u[2]; bf16x8 v; } Th0, Tl0, Th1, Tl1;
            {
                const unsigned short* hp = qh_w + (mt * 16 + li) * 68 + lg * 8;
                const unsigned short* lp = ql_w + (mt * 16 + li) * 68 + lg * 8;
                Th0.u[0] = *(const uint2*)hp;        Th0.u[1] = *(const uint2*)(hp + 4);
                Tl0.u[0] = *(const uint2*)lp;        Tl0.u[1] = *(const uint2*)(lp + 4);
                Th1.u[0] = *(const uint2*)(hp + 32); Th1.u[1] = *(const uint2*)(hp + 36);
                Tl1.u[0] = *(const uint2*)(lp + 32); Tl1.u[1] = *(const uint2*)(lp + 36);
            }
            #pragma unroll
            for (int ntile = 0; ntile < 2; ++ntile) {
                f32x4 sacc = {0, 0, 0, 0};
                sacc = __builtin_amdgcn_mfma_f32_16x16x32_bf16(Th0.v, fah[ntile][0], sacc, 0, 0, 0);
                sacc = __builtin_amdgcn_mfma_f32_16x16x32_bf16(Tl0.v, fah[ntile][0], sacc, 0, 0, 0);
                sacc = __builtin_amdgcn_mfma_f32_16x16x32_bf16(Th0.v, fal[ntile][0], sacc, 0, 0, 0);
                sacc = __builtin_amdgcn_mfma_f32_16x16x32_bf16(Th1.v, fah[ntile][1], sacc, 0, 0, 0);
                sacc = __builtin_amdgcn_mfma_f32_16x16x32_bf16(Tl1.v, fah[ntile][1], sacc, 0, 0, 0);
                sacc = __builtin_amdgcn_mfma_f32_16x16x32_bf16(Th1.v, fal[ntile][1], sacc, 0, 0, 0);
                int u = ntile * 16 + li;
                #pragma unroll
                for (int r = 0; r < 4; ++r) {
                    int s = mt * 16 + lg * 4 + r;
                    float rq = __shfl(rowqv, hh * 22 + (s < 22 ? s : 0));
                    if (s < 22 && u < 22)
                        P[s * 22 + u] = sacc[r] + rq;
                }
            }
        }
        {
            int r2 = lane >> 1, c2 = lane & 1;
            float pm = -1e30f, psum = 0.f;
            if (lane < 44) {
                #pragma unroll
                for (int j = 0; j < 11; ++j) pm = fmaxf(pm, P[r2 * 22 + c2 * 11 + j]);
            }
            float m = fmaxf(__shfl(pm, 2 * lane), __shfl(pm, 2 * lane + 1)); // lane<22
            float rm = __shfl(m, r2);
            if (lane < 44) {
                #pragma unroll
                for (int j = 0; j < 11; ++j) {
                    int idx = r2 * 22 + c2 * 11 + j;
                    float ev = __expf(P[idx] - rm);
                    P[idx] = ev;
                    psum += ev;
                }
            }
            float sum = __shfl(psum, 2 * lane) + __shfl(psum, 2 * lane + 1);  // lane<22
            float rinv = 1.f / sum;
            float a = 0.f;
            #pragma unroll
            for (int s = 0; s < 22; ++s) {
                float rv = __shfl(rinv, s);
                if (lane < 22) a = fmaf(P[s * 22 + lane], rv, a);
            }
            float av = a * (1.f / 22.f);
            float acc = 0.f;
            #pragma unroll
            for (int u = 0; u < 22; ++u) {
                float au = __shfl(av, u);
                acc = fmaf(au, unpk_f32(f_p[u * 68 + lane]), acc);
            }
            fbar_s[h * 64 + lane] = acc;
        }
    }
    __syncthreads();
    {
        int d = t & 63, part = t >> 6;
        const float* wc = ws + OFF_WC;
        float acc = 0.f;
        for (int j = part * 128; j < part * 128 + 128; ++j)
            acc = fmaf(fbar_s[j], wc[j * 64 + d], acc);
        fred[part * 64 + d] = acc;
    }
    __syncthreads();
    if (t < 64)
        out[(size_t)b * 64 + t] = ws[OFF_CBIAS + t]
            + fred[t] + fred[64 + t] + fred[128 + t] + fred[192 + t];
}

extern "C" void kernel_launch(void* const* d_in, const int* in_sizes, int n_in,
                              void* d_out, int out_size, void* d_ws, size_t ws_size,
                              hipStream_t stream) {
    const float* audio1 = (const float*)d_in[0];
    const float* audio2 = (const float*)d_in[1];
    const float* w1   = (const float*)d_in[2];
    const float* b1   = (const float*)d_in[3];
    const float* g1   = (const float*)d_in[4];
    const float* be1  = (const float*)d_in[5];
    const float* m1   = (const float*)d_in[6];
    const float* v1   = (const float*)d_in[7];
    const float* w2   = (const float*)d_in[8];
    const float* b2   = (const float*)d_in[9];
    const float* g2   = (const float*)d_in[10];
    const float* be2  = (const float*)d_in[11];
    const float* m2   = (const float*)d_in[12];
    const float* v2   = (const float*)d_in[13];
    const float* w3   = (const float*)d_in[14];
    const float* b3   = (const float*)d_in[15];
    const float* g3   = (const float*)d_in[16];
    const float* be3  = (const float*)d_in[17];
    const float* m3   = (const float*)d_in[18];
    const float* v3   = (const float*)d_in[19];
    const float* Wq   = (const float*)d_in[20];
    const float* bq   = (const float*)d_in[21];
    const float* Wk   = (const float*)d_in[22];
    const float* bk   = (const float*)d_in[23];
    const float* Wv   = (const float*)d_in[24];
    const float* bv   = (const float*)d_in[25];
    const float* Wfc  = (const float*)d_in[26];
    const float* bfc  = (const float*)d_in[27];
    const float* Wout = (const float*)d_in[28];
    const float* bout = (const float*)d_in[29];

    float* ws  = (float*)d_ws;
    float* out = (float*)d_out;
    int B = in_sizes[0] / SEQLEN;   // 4096
    int nseq = 2 * B;
    int ntri = (nseq * 5 + 2) / 3;  // three tiles per block

    repack_kernel<<<(REPACK_N + 255) / 256, 256, 0, stream>>>(
        w1, w2, w3, Wq, Wk, Wv, Wfc, Wout, bq, bk, ws);
    repack2_kernel<<<128, 256, 0, stream>>>(Wv, ws);
    cbias_kernel<<<1, 64, 0, stream>>>(Wfc, Wout, bfc, bout, bv, ws);
    encoder_kernel<<<ntri, 256, 0, stream>>>(audio1, audio2,
        b1, g1, be1, m1, v1,
        b2, g2, be2, m2, v2,
        b3, g3, be3, m3, v3,
        ws, B);
    mha_kernel<<<nseq, 256, 0, stream>>>(ws, out, B);
}